// Round 1
// baseline (707.793 us; speedup 1.0000x reference)
//
#include <hip/hip_runtime.h>

#define BB 4
#define TT 4096
#define HH 2048
#define NSLOT 64
#define KD 256
#define VD 256
#define BT (BB*TT)
#define NEGV (-1e9f)
#define EPSV 1e-5f

// ---------------- mask dtype detection + conversion ----------------
// jax bool masks may arrive as int32, float32, or packed uint8. Detect from
// the byte pattern of valid_mask (256 elements, ~half true):
//  - int32 0/1: every 32-bit word is 0 or 1
//  - float32:   words are 0x3F800000 or 0
//  - uint8:     words are packings of 0x00/0x01 bytes (not all in {0,1})
__global__ void mask_convert_kernel(const void* valid_raw, const void* hist_raw,
                                    int* valid_int, int* hist_int) {
  __shared__ int mode_s;
  const int tid = threadIdx.x;
  if (tid == 0) {
    const unsigned int* w = (const unsigned int*)valid_raw;
    int all01 = 1, anyfloat = 0;
    for (int i = 0; i < 64; ++i) {  // 256 bytes: safe under every candidate dtype
      unsigned int x = w[i];
      if (x != 0u && x != 1u) all01 = 0;
      if (x == 0x3F800000u) anyfloat = 1;
    }
    mode_s = all01 ? 0 : (anyfloat ? 1 : 2);
  }
  __syncthreads();
  const int mode = mode_s;
  {
    const int* vi = (const int*)valid_raw;
    const float* vf = (const float*)valid_raw;
    const unsigned char* vb = (const unsigned char*)valid_raw;
    for (int i = tid; i < BB * NSLOT; i += blockDim.x)
      valid_int[i] = (mode == 0) ? (vi[i] != 0)
                   : (mode == 1) ? (vf[i] != 0.0f)
                                 : (vb[i] != 0);
  }
  {
    const int* vi = (const int*)hist_raw;
    const float* vf = (const float*)hist_raw;
    const unsigned char* vb = (const unsigned char*)hist_raw;
    for (int i = tid; i < BB * TT; i += blockDim.x)
      hist_int[i] = (mode == 0) ? (vi[i] != 0)
                  : (mode == 1) ? (vf[i] != 0.0f)
                                : (vb[i] != 0);
  }
}

// ---------------- tiled fp32 GEMM: C[m,n] = sum_k A[m,k]*Bm[n,k] (+RES) ------
// A: [16384 x KDIM_] row-major, Bm: [NDIM_ x KDIM_] row-major (reduction contiguous)
// tile 64x64, BK=32, 256 threads, 4x4 micro-tile per thread
template<int KDIM_, int NDIM_, bool FUSE>
__global__ __launch_bounds__(256) void sgemm_tt_kernel(
    const float* __restrict__ A,
    const float* __restrict__ Bm,
    const float* __restrict__ RES,
    float* __restrict__ C) {
  constexpr int BK = 32;
  constexpr int NT = NDIM_ / 64;
  // pitch 68: 68*4=272 bytes, 16B-aligned rows -> ds_read_b128 ok, breaks most conflicts
  __shared__ float As[BK][68];
  __shared__ float Bs[BK][68];
  const int bm = blockIdx.x / NT;
  const int bn = blockIdx.x % NT;
  const int tid = threadIdx.x;
  const int tn = (tid & 15) * 4;   // column within tile (fast dim -> coalesced C store)
  const int tm = (tid >> 4) * 4;   // row within tile
  const int row0 = bm * 64, col0 = bn * 64;
  float acc[4][4] = {};

  for (int k0 = 0; k0 < KDIM_; k0 += BK) {
#pragma unroll
    for (int it = 0; it < 2; ++it) {
      const int idx = tid + it * 256;
      const int r = idx >> 3;          // 0..63
      const int k4 = (idx & 7) * 4;    // 0..28
      const float4 va = *(const float4*)&A[(size_t)(row0 + r) * KDIM_ + k0 + k4];
      As[k4 + 0][r] = va.x; As[k4 + 1][r] = va.y;
      As[k4 + 2][r] = va.z; As[k4 + 3][r] = va.w;
      const float4 vb = *(const float4*)&Bm[(size_t)(col0 + r) * KDIM_ + k0 + k4];
      Bs[k4 + 0][r] = vb.x; Bs[k4 + 1][r] = vb.y;
      Bs[k4 + 2][r] = vb.z; Bs[k4 + 3][r] = vb.w;
    }
    __syncthreads();
#pragma unroll
    for (int kk = 0; kk < BK; ++kk) {
      const float4 a = *(const float4*)&As[kk][tm];
      const float4 b = *(const float4*)&Bs[kk][tn];
      acc[0][0] += a.x * b.x; acc[0][1] += a.x * b.y; acc[0][2] += a.x * b.z; acc[0][3] += a.x * b.w;
      acc[1][0] += a.y * b.x; acc[1][1] += a.y * b.y; acc[1][2] += a.y * b.z; acc[1][3] += a.y * b.w;
      acc[2][0] += a.z * b.x; acc[2][1] += a.z * b.y; acc[2][2] += a.z * b.z; acc[2][3] += a.z * b.w;
      acc[3][0] += a.w * b.x; acc[3][1] += a.w * b.y; acc[3][2] += a.w * b.z; acc[3][3] += a.w * b.w;
    }
    __syncthreads();
  }

#pragma unroll
  for (int i = 0; i < 4; ++i) {
    const size_t off = (size_t)(row0 + tm + i) * NDIM_ + col0 + tn;
    float4 c;
    c.x = acc[i][0]; c.y = acc[i][1]; c.z = acc[i][2]; c.w = acc[i][3];
    if constexpr (FUSE) {
      const float4 r4 = *(const float4*)&RES[off];
      c.x += r4.x; c.y += r4.y; c.z += r4.z; c.w += r4.w;
    }
    *(float4*)&C[off] = c;
  }
}

// ---------------- attention: scores -> masked softmax -> retrieve ------------
// one wave (64 threads) per token
__global__ __launch_bounds__(64) void attn_kernel(
    const float* __restrict__ query,   // [BT,256]
    const float* __restrict__ keys,    // [B,64,256]
    const float* __restrict__ vals,    // [B,64,256]
    const int* __restrict__ valid,     // [B,64]
    const int* __restrict__ hist,      // [B,T] (flat == token index)
    float* __restrict__ retr) {        // [BT,256]
  const int tglob = blockIdx.x;
  const int b = tglob >> 12;           // T=4096
  const int lane = threadIdx.x;
  __shared__ __align__(16) float q[256];
  __shared__ float w[64];

#pragma unroll
  for (int j = 0; j < 4; ++j)
    q[lane + 64 * j] = query[(size_t)tglob * 256 + lane + 64 * j];
  __syncthreads();

  // score for slot n = lane
  const float* krow = &keys[((size_t)b * 64 + lane) * 256];
  float s = 0.0f;
#pragma unroll 4
  for (int k4 = 0; k4 < 64; ++k4) {
    const float4 qa = *(const float4*)&q[k4 * 4];
    const float4 ka = *(const float4*)&krow[k4 * 4];
    s += qa.x * ka.x + qa.y * ka.y + qa.z * ka.z + qa.w * ka.w;
  }
  const int v = valid[b * 64 + lane];
  const unsigned long long bal = __ballot(v != 0);
  const float any = (bal != 0ull) ? 1.0f : 0.0f;
  s = v ? s : NEGV;

  float m = s;
#pragma unroll
  for (int o = 32; o; o >>= 1) m = fmaxf(m, __shfl_xor(m, o));
  const float e = __expf(s - m);
  float sum = e;
#pragma unroll
  for (int o = 32; o; o >>= 1) sum += __shfl_xor(sum, o);
  w[lane] = e / sum * any;
  __syncthreads();

  const float allowed = hist[tglob] ? 0.0f : 1.0f;
  float acc[4] = {0.f, 0.f, 0.f, 0.f};
  const float* vb = &vals[(size_t)b * 64 * 256];
  for (int n = 0; n < 64; ++n) {
    const float wn = w[n];
#pragma unroll
    for (int j = 0; j < 4; ++j)
      acc[j] += wn * vb[n * 256 + 64 * j + lane];
  }
#pragma unroll
  for (int j = 0; j < 4; ++j)
    retr[(size_t)tglob * 256 + 64 * j + lane] = acc[j] * allowed;
}

// ---------------- row LayerNorm (in place on x = hs + merged) ----------------
__global__ __launch_bounds__(256) void ln_kernel(float* x,
                                                 const float* __restrict__ gamma,
                                                 const float* __restrict__ beta) {
  const int row = blockIdx.x;
  const int tid = threadIdx.x;
  float* xr = x + (size_t)row * HH;
  const float4 v0 = *(const float4*)&xr[tid * 4];
  const float4 v1 = *(const float4*)&xr[1024 + tid * 4];
  float sum = v0.x + v0.y + v0.z + v0.w + v1.x + v1.y + v1.z + v1.w;
  float ss  = v0.x * v0.x + v0.y * v0.y + v0.z * v0.z + v0.w * v0.w
            + v1.x * v1.x + v1.y * v1.y + v1.z * v1.z + v1.w * v1.w;
#pragma unroll
  for (int o = 32; o; o >>= 1) {
    sum += __shfl_xor(sum, o);
    ss  += __shfl_xor(ss, o);
  }
  __shared__ float red[4][2];
  const int wid = tid >> 6;
  if ((tid & 63) == 0) { red[wid][0] = sum; red[wid][1] = ss; }
  __syncthreads();
  sum = red[0][0] + red[1][0] + red[2][0] + red[3][0];
  ss  = red[0][1] + red[1][1] + red[2][1] + red[3][1];
  const float mu = sum * (1.0f / HH);
  const float var = ss * (1.0f / HH) - mu * mu;
  const float inv = rsqrtf(var + EPSV);

  const float4 g0 = *(const float4*)&gamma[tid * 4];
  const float4 b0 = *(const float4*)&beta[tid * 4];
  const float4 g1 = *(const float4*)&gamma[1024 + tid * 4];
  const float4 b1 = *(const float4*)&beta[1024 + tid * 4];
  float4 o0, o1;
  o0.x = (v0.x - mu) * inv * g0.x + b0.x;
  o0.y = (v0.y - mu) * inv * g0.y + b0.y;
  o0.z = (v0.z - mu) * inv * g0.z + b0.z;
  o0.w = (v0.w - mu) * inv * g0.w + b0.w;
  o1.x = (v1.x - mu) * inv * g1.x + b1.x;
  o1.y = (v1.y - mu) * inv * g1.y + b1.y;
  o1.z = (v1.z - mu) * inv * g1.z + b1.z;
  o1.w = (v1.w - mu) * inv * g1.w + b1.w;
  *(float4*)&xr[tid * 4] = o0;
  *(float4*)&xr[1024 + tid * 4] = o1;
}

extern "C" void kernel_launch(void* const* d_in, const int* in_sizes, int n_in,
                              void* d_out, int out_size, void* d_ws, size_t ws_size,
                              hipStream_t stream) {
  const float* hs    = (const float*)d_in[0];
  const float* keys  = (const float*)d_in[1];
  const float* vals  = (const float*)d_in[2];
  const float* Wq    = (const float*)d_in[3];
  const float* Wo    = (const float*)d_in[4];
  const float* gamma = (const float*)d_in[5];
  const float* beta  = (const float*)d_in[6];
  const void* valid_raw = d_in[7];
  const void* hist_raw  = d_in[8];
  float* out = (float*)d_out;

  float* query = (float*)d_ws;                       // 16384*256 f32 = 16.8 MB
  float* retr  = query + (size_t)BT * KD;            // 16384*256 f32 = 16.8 MB
  int* valid_int = (int*)(retr + (size_t)BT * VD);   // 256 ints
  int* hist_int  = valid_int + BB * NSLOT;           // 16384 ints

  mask_convert_kernel<<<dim3(1), dim3(256), 0, stream>>>(valid_raw, hist_raw,
                                                         valid_int, hist_int);
  // GEMM1: query = hs[16384x2048] . Wq^T[2048x256]
  sgemm_tt_kernel<HH, KD, false>
      <<<dim3((BT / 64) * (KD / 64)), dim3(256), 0, stream>>>(hs, Wq, nullptr, query);
  // attention per token
  attn_kernel<<<dim3(BT), dim3(64), 0, stream>>>(query, keys, vals,
                                                 valid_int, hist_int, retr);
  // GEMM2 (+residual): out = retr[16384x256] . Wo^T[256x2048] + hs
  sgemm_tt_kernel<VD, HH, true>
      <<<dim3((BT / 64) * (HH / 64)), dim3(256), 0, stream>>>(retr, Wo, hs, out);
  // LayerNorm rows in place
  ln_kernel<<<dim3(BT), dim3(256), 0, stream>>>(out, gamma, beta);
}

// Round 2
// 344.395 us; speedup vs baseline: 2.0552x; 2.0552x over previous
//
#include <hip/hip_runtime.h>
#include <hip/hip_bf16.h>

#define BB 4
#define TT 4096
#define HH 2048
#define NSLOT 64
#define KD 256
#define VD 256
#define BT (BB*TT)
#define NEGV (-1e9f)
#define EPSV 1e-5f

typedef __attribute__((ext_vector_type(8))) short short8;
typedef __attribute__((ext_vector_type(4))) float floatx4;

// ---------------- mask dtype detection + conversion ----------------
__global__ void mask_convert_kernel(const void* valid_raw, const void* hist_raw,
                                    int* valid_int, int* hist_int) {
  __shared__ int mode_s;
  const int tid = threadIdx.x;
  if (tid == 0) {
    const unsigned int* w = (const unsigned int*)valid_raw;
    int all01 = 1, anyfloat = 0;
    for (int i = 0; i < 64; ++i) {
      unsigned int x = w[i];
      if (x != 0u && x != 1u) all01 = 0;
      if (x == 0x3F800000u) anyfloat = 1;
    }
    mode_s = all01 ? 0 : (anyfloat ? 1 : 2);
  }
  __syncthreads();
  const int mode = mode_s;
  {
    const int* vi = (const int*)valid_raw;
    const float* vf = (const float*)valid_raw;
    const unsigned char* vb = (const unsigned char*)valid_raw;
    for (int i = tid; i < BB * NSLOT; i += blockDim.x)
      valid_int[i] = (mode == 0) ? (vi[i] != 0)
                   : (mode == 1) ? (vf[i] != 0.0f)
                                 : (vb[i] != 0);
  }
  {
    const int* vi = (const int*)hist_raw;
    const float* vf = (const float*)hist_raw;
    const unsigned char* vb = (const unsigned char*)hist_raw;
    for (int i = tid; i < BB * TT; i += blockDim.x)
      hist_int[i] = (mode == 0) ? (vi[i] != 0)
                  : (mode == 1) ? (vf[i] != 0.0f)
                                : (vb[i] != 0);
  }
}

// ---------------- PK[b,n,h] = sum_k keys[b,n,k] * Wq[k,h]  (fp32) -----------
// grid 128: b = blk>>5, h0 = (blk&31)*64; 256 threads
__global__ __launch_bounds__(256) void pk_kernel(const float* __restrict__ keys,
                                                 const float* __restrict__ Wq,
                                                 float* __restrict__ PK) {
  const int b = blockIdx.x >> 5;
  const int h0 = (blockIdx.x & 31) * 64;
  __shared__ float ks[64][256];
  const int tid = threadIdx.x;
  const float* kb = keys + (size_t)b * 64 * 256;
  for (int i = tid; i < 64 * 64; i += 256) {       // i indexes float4
    const int n = i >> 6, k4 = (i & 63) * 4;
    *(float4*)&ks[n][k4] = *(const float4*)&kb[n * 256 + k4];
  }
  __syncthreads();
  const int h = h0 + (tid & 63);
  const int ng = tid >> 6;                         // 0..3
  float acc[16] = {};
  for (int k = 0; k < 256; ++k) {
    const float wq = Wq[(size_t)k * HH + h];
#pragma unroll
    for (int i = 0; i < 16; ++i) acc[i] += ks[i * 4 + ng][k] * wq;
  }
#pragma unroll
  for (int i = 0; i < 16; ++i)
    PK[((size_t)b * 64 + i * 4 + ng) * HH + h] = acc[i];
}

// ---------------- Wo fp32 -> bf16 ----------------
__global__ __launch_bounds__(256) void wo_bf16_kernel(const float* __restrict__ Wo,
                                                      __hip_bfloat16* __restrict__ WoB) {
  const int i = (blockIdx.x * 256 + threadIdx.x) * 4;
  const float4 v = *(const float4*)&Wo[i];
  WoB[i + 0] = __float2bfloat16(v.x);
  WoB[i + 1] = __float2bfloat16(v.y);
  WoB[i + 2] = __float2bfloat16(v.z);
  WoB[i + 3] = __float2bfloat16(v.w);
}

// ---------------- fused: scores(fp32) -> softmax -> retrieve -> bf16 --------
// 64 tokens/block, 512 threads (8 waves). scores[64 tok][64 slot] over H=2048.
__global__ __launch_bounds__(512) void attn_fused_kernel(
    const float* __restrict__ hs,      // [BT,2048]
    const float* __restrict__ PK,      // [B,64,2048]
    const float* __restrict__ vals,    // [B,64,256]
    const int* __restrict__ valid,     // [B,64]
    const int* __restrict__ hist,      // [BT]
    __hip_bfloat16* __restrict__ retrB) { // [BT,256]
  const int t0 = blockIdx.x * 64;
  const int b = t0 >> 12;
  const int tid = threadIdx.x;
  __shared__ float As[32][68];   // hs tile, k-major: As[k][token]
  __shared__ float Bs[32][68];   // PK tile, k-major: Bs[k][slot]
  __shared__ float sc[64][65];   // scores then weights

  const int tn = (tid & 15) * 4;       // slot
  const int tm = (tid >> 4) * 2;       // token
  float acc[2][4] = {};

  const float* pkb = PK + (size_t)b * 64 * HH;
  const int r = tid >> 3;              // 0..63
  const int k4 = (tid & 7) * 4;        // 0..28

  for (int k0 = 0; k0 < HH; k0 += 32) {
    const float4 va = *(const float4*)&hs[(size_t)(t0 + r) * HH + k0 + k4];
    const float4 vb = *(const float4*)&pkb[(size_t)r * HH + k0 + k4];
    __syncthreads();
    As[k4 + 0][r] = va.x; As[k4 + 1][r] = va.y;
    As[k4 + 2][r] = va.z; As[k4 + 3][r] = va.w;
    Bs[k4 + 0][r] = vb.x; Bs[k4 + 1][r] = vb.y;
    Bs[k4 + 2][r] = vb.z; Bs[k4 + 3][r] = vb.w;
    __syncthreads();
#pragma unroll
    for (int kk = 0; kk < 32; ++kk) {
      const float2 a2 = *(const float2*)&As[kk][tm];
      const float4 b4 = *(const float4*)&Bs[kk][tn];
      acc[0][0] += a2.x * b4.x; acc[0][1] += a2.x * b4.y;
      acc[0][2] += a2.x * b4.z; acc[0][3] += a2.x * b4.w;
      acc[1][0] += a2.y * b4.x; acc[1][1] += a2.y * b4.y;
      acc[1][2] += a2.y * b4.z; acc[1][3] += a2.y * b4.w;
    }
  }
  __syncthreads();
#pragma unroll
  for (int i = 0; i < 2; ++i)
#pragma unroll
    for (int j = 0; j < 4; ++j)
      sc[tm + i][tn + j] = acc[i][j];
  __syncthreads();

  // softmax: 8 waves x 8 tokens
  const int wid = tid >> 6, lane = tid & 63;
  const int vmy = valid[b * 64 + lane];
  const unsigned long long bal = __ballot(vmy != 0);
  const float any = (bal != 0ull) ? 1.0f : 0.0f;
#pragma unroll
  for (int i = 0; i < 8; ++i) {
    const int tt = wid * 8 + i;
    float s = vmy ? sc[tt][lane] : NEGV;
    float m = s;
#pragma unroll
    for (int o = 32; o; o >>= 1) m = fmaxf(m, __shfl_xor(m, o));
    const float e = __expf(s - m);
    float sum = e;
#pragma unroll
    for (int o = 32; o; o >>= 1) sum += __shfl_xor(sum, o);
    sc[tt][lane] = e / sum * any;
  }
  __syncthreads();

  // retrieve: per wave, its 8 tokens in 2 chunks of 4
  const float* vb = vals + (size_t)b * 64 * 256;
#pragma unroll
  for (int c = 0; c < 2; ++c) {
    const int tb = wid * 8 + c * 4;
    float a4[4][4] = {};
    for (int n = 0; n < 64; ++n) {
      const float v0 = vb[n * 256 + lane];
      const float v1 = vb[n * 256 + 64 + lane];
      const float v2 = vb[n * 256 + 128 + lane];
      const float v3 = vb[n * 256 + 192 + lane];
#pragma unroll
      for (int i = 0; i < 4; ++i) {
        const float w = sc[tb + i][n];
        a4[i][0] += w * v0; a4[i][1] += w * v1;
        a4[i][2] += w * v2; a4[i][3] += w * v3;
      }
    }
#pragma unroll
    for (int i = 0; i < 4; ++i) {
      const int tok = t0 + tb + i;
      const float allowed = hist[tok] ? 0.0f : 1.0f;
#pragma unroll
      for (int j = 0; j < 4; ++j)
        retrB[(size_t)tok * 256 + j * 64 + lane] =
            __float2bfloat16(a4[i][j] * allowed);
    }
  }
}

// ---------------- GEMM2 bf16 MFMA: x = retrB . WoB^T + hs -------------------
// C[16384x2048], A[16384x256] bf16, B[2048x256] bf16 (contraction contiguous)
// 128x128 tile, 4 waves (2x2), BK=32, K=256
__global__ __launch_bounds__(256) void gemm2_mfma_kernel(
    const __hip_bfloat16* __restrict__ A,
    const __hip_bfloat16* __restrict__ Bw,
    const float* __restrict__ RES,
    float* __restrict__ C) {
  const int bm = blockIdx.x >> 4;
  const int bn = blockIdx.x & 15;
  const int tid = threadIdx.x;
  const int wid = tid >> 6, lane = tid & 63;
  const int wr = wid >> 1, wc = wid & 1;
  __shared__ __hip_bfloat16 A_s[128][40];  // pad 32->40 (80B row stride)
  __shared__ __hip_bfloat16 B_s[128][40];
  floatx4 acc[4][4];
#pragma unroll
  for (int m = 0; m < 4; ++m)
#pragma unroll
    for (int n = 0; n < 4; ++n) acc[m][n] = (floatx4){0.f, 0.f, 0.f, 0.f};

  const int row0 = bm * 128, col0 = bn * 128;
  const int sr = tid >> 1, sk = (tid & 1) * 16;
  const int fk = (lane >> 4) * 8;
  const int fr = lane & 15;

  for (int k0 = 0; k0 < 256; k0 += 32) {
    const float4* ga = (const float4*)&A[(size_t)(row0 + sr) * 256 + k0 + sk];
    const float4 va0 = ga[0], va1 = ga[1];
    const float4* gb = (const float4*)&Bw[(size_t)(col0 + sr) * 256 + k0 + sk];
    const float4 vb0 = gb[0], vb1 = gb[1];
    __syncthreads();
    *(float4*)&A_s[sr][sk] = va0; *(float4*)&A_s[sr][sk + 8] = va1;
    *(float4*)&B_s[sr][sk] = vb0; *(float4*)&B_s[sr][sk + 8] = vb1;
    __syncthreads();
    short8 af[4], bf[4];
#pragma unroll
    for (int m = 0; m < 4; ++m)
      af[m] = *(const short8*)&A_s[wr * 64 + m * 16 + fr][fk];
#pragma unroll
    for (int n = 0; n < 4; ++n)
      bf[n] = *(const short8*)&B_s[wc * 64 + n * 16 + fr][fk];
#pragma unroll
    for (int m = 0; m < 4; ++m)
#pragma unroll
      for (int n = 0; n < 4; ++n)
        acc[m][n] = __builtin_amdgcn_mfma_f32_16x16x32_bf16(af[m], bf[n],
                                                            acc[m][n], 0, 0, 0);
  }

  const int crow0 = row0 + wr * 64 + (lane >> 4) * 4;
  const int ccol0 = col0 + wc * 64 + fr;
#pragma unroll
  for (int m = 0; m < 4; ++m)
#pragma unroll
    for (int n = 0; n < 4; ++n)
#pragma unroll
      for (int rr = 0; rr < 4; ++rr) {
        const int row = crow0 + m * 16 + rr;
        const int col = ccol0 + n * 16;
        const size_t off = (size_t)row * HH + col;
        C[off] = acc[m][n][rr] + RES[off];
      }
}

// ---------------- row LayerNorm in place ----------------
__global__ __launch_bounds__(256) void ln_kernel(float* x,
                                                 const float* __restrict__ gamma,
                                                 const float* __restrict__ beta) {
  const int row = blockIdx.x;
  const int tid = threadIdx.x;
  float* xr = x + (size_t)row * HH;
  const float4 v0 = *(const float4*)&xr[tid * 4];
  const float4 v1 = *(const float4*)&xr[1024 + tid * 4];
  float sum = v0.x + v0.y + v0.z + v0.w + v1.x + v1.y + v1.z + v1.w;
  float ss  = v0.x * v0.x + v0.y * v0.y + v0.z * v0.z + v0.w * v0.w
            + v1.x * v1.x + v1.y * v1.y + v1.z * v1.z + v1.w * v1.w;
#pragma unroll
  for (int o = 32; o; o >>= 1) {
    sum += __shfl_xor(sum, o);
    ss  += __shfl_xor(ss, o);
  }
  __shared__ float red[4][2];
  const int wid = tid >> 6;
  if ((tid & 63) == 0) { red[wid][0] = sum; red[wid][1] = ss; }
  __syncthreads();
  sum = red[0][0] + red[1][0] + red[2][0] + red[3][0];
  ss  = red[0][1] + red[1][1] + red[2][1] + red[3][1];
  const float mu = sum * (1.0f / HH);
  const float var = ss * (1.0f / HH) - mu * mu;
  const float inv = rsqrtf(var + EPSV);

  const float4 g0 = *(const float4*)&gamma[tid * 4];
  const float4 b0 = *(const float4*)&beta[tid * 4];
  const float4 g1 = *(const float4*)&gamma[1024 + tid * 4];
  const float4 b1 = *(const float4*)&beta[1024 + tid * 4];
  float4 o0, o1;
  o0.x = (v0.x - mu) * inv * g0.x + b0.x;
  o0.y = (v0.y - mu) * inv * g0.y + b0.y;
  o0.z = (v0.z - mu) * inv * g0.z + b0.z;
  o0.w = (v0.w - mu) * inv * g0.w + b0.w;
  o1.x = (v1.x - mu) * inv * g1.x + b1.x;
  o1.y = (v1.y - mu) * inv * g1.y + b1.y;
  o1.z = (v1.z - mu) * inv * g1.z + b1.z;
  o1.w = (v1.w - mu) * inv * g1.w + b1.w;
  *(float4*)&xr[tid * 4] = o0;
  *(float4*)&xr[1024 + tid * 4] = o1;
}

extern "C" void kernel_launch(void* const* d_in, const int* in_sizes, int n_in,
                              void* d_out, int out_size, void* d_ws, size_t ws_size,
                              hipStream_t stream) {
  const float* hs    = (const float*)d_in[0];
  const float* keys  = (const float*)d_in[1];
  const float* vals  = (const float*)d_in[2];
  const float* Wq    = (const float*)d_in[3];
  const float* Wo    = (const float*)d_in[4];
  const float* gamma = (const float*)d_in[5];
  const float* beta  = (const float*)d_in[6];
  const void* valid_raw = d_in[7];
  const void* hist_raw  = d_in[8];
  float* out = (float*)d_out;

  char* w = (char*)d_ws;
  float* PK = (float*)w;                                        // 2 MB
  __hip_bfloat16* WoB = (__hip_bfloat16*)(w + (2u << 20));      // 1 MB
  __hip_bfloat16* retrB = (__hip_bfloat16*)(w + (3u << 20));    // 8 MB
  int* valid_int = (int*)(w + (11u << 20));
  int* hist_int = valid_int + BB * NSLOT;

  mask_convert_kernel<<<dim3(1), dim3(256), 0, stream>>>(valid_raw, hist_raw,
                                                         valid_int, hist_int);
  pk_kernel<<<dim3(128), dim3(256), 0, stream>>>(keys, Wq, PK);
  wo_bf16_kernel<<<dim3(512), dim3(256), 0, stream>>>(Wo, WoB);
  attn_fused_kernel<<<dim3(BT / 64), dim3(512), 0, stream>>>(
      hs, PK, vals, valid_int, hist_int, retrB);
  gemm2_mfma_kernel<<<dim3((BT / 128) * (HH / 128)), dim3(256), 0, stream>>>(
      retrB, WoB, hs, out);
  ln_kernel<<<dim3(BT), dim3(256), 0, stream>>>(out, gamma, beta);
}

// Round 3
// 274.840 us; speedup vs baseline: 2.5753x; 1.2531x over previous
//
#include <hip/hip_runtime.h>
#include <hip/hip_bf16.h>

#define BB 4
#define TT 4096
#define HH 2048
#define NSLOT 64
#define KD 256
#define VD 256
#define BT (BB*TT)
#define NEGV (-1e9f)
#define EPSV 1e-5f

typedef __attribute__((ext_vector_type(8))) short short8;
typedef __attribute__((ext_vector_type(4))) float floatx4;

union B8 { short8 v; unsigned short u[8]; };

__device__ inline unsigned short f2bf(float x) {
  unsigned u = __float_as_uint(x);
  return (unsigned short)((u + 0x7FFFu + ((u >> 16) & 1u)) >> 16);
}
__device__ inline float bf2f(unsigned short h) {
  return __uint_as_float(((unsigned)h) << 16);
}
// 8 fp32 -> hi/lo bf16 (hi = RNE(x), lo = RNE(x - hi))
__device__ inline void cvt8(const float4 a, const float4 b, B8& h, B8& l) {
  const float f[8] = {a.x, a.y, a.z, a.w, b.x, b.y, b.z, b.w};
#pragma unroll
  for (int j = 0; j < 8; ++j) {
    unsigned short hh = f2bf(f[j]);
    h.u[j] = hh;
    l.u[j] = f2bf(f[j] - bf2f(hh));
  }
}

// ---------------- mask dtype detection + conversion ----------------
__global__ void mask_convert_kernel(const void* valid_raw, const void* hist_raw,
                                    int* valid_int, int* hist_int) {
  __shared__ int mode_s;
  const int tid = threadIdx.x;
  if (tid == 0) {
    const unsigned int* w = (const unsigned int*)valid_raw;
    int all01 = 1, anyfloat = 0;
    for (int i = 0; i < 64; ++i) {
      unsigned int x = w[i];
      if (x != 0u && x != 1u) all01 = 0;
      if (x == 0x3F800000u) anyfloat = 1;
    }
    mode_s = all01 ? 0 : (anyfloat ? 1 : 2);
  }
  __syncthreads();
  const int mode = mode_s;
  {
    const int* vi = (const int*)valid_raw;
    const float* vf = (const float*)valid_raw;
    const unsigned char* vb = (const unsigned char*)valid_raw;
    for (int i = tid; i < BB * NSLOT; i += blockDim.x)
      valid_int[i] = (mode == 0) ? (vi[i] != 0)
                   : (mode == 1) ? (vf[i] != 0.0f)
                                 : (vb[i] != 0);
  }
  {
    const int* vi = (const int*)hist_raw;
    const float* vf = (const float*)hist_raw;
    const unsigned char* vb = (const unsigned char*)hist_raw;
    for (int i = tid; i < BB * TT; i += blockDim.x)
      hist_int[i] = (mode == 0) ? (vi[i] != 0)
                  : (mode == 1) ? (vf[i] != 0.0f)
                                : (vb[i] != 0);
  }
}

// ---------------- PK[b,n,h] = sum_k keys[b,n,k] * Wq[k,h]  (fp32) -----------
__global__ __launch_bounds__(256) void pk_kernel(const float* __restrict__ keys,
                                                 const float* __restrict__ Wq,
                                                 float* __restrict__ PK) {
  const int b = blockIdx.x >> 5;
  const int h0 = (blockIdx.x & 31) * 64;
  __shared__ float ks[64][256];
  const int tid = threadIdx.x;
  const float* kb = keys + (size_t)b * 64 * 256;
  for (int i = tid; i < 64 * 64; i += 256) {
    const int n = i >> 6, k4 = (i & 63) * 4;
    *(float4*)&ks[n][k4] = *(const float4*)&kb[n * 256 + k4];
  }
  __syncthreads();
  const int h = h0 + (tid & 63);
  const int ng = tid >> 6;
  float acc[16] = {};
  for (int k = 0; k < 256; ++k) {
    const float wq = Wq[(size_t)k * HH + h];
#pragma unroll
    for (int i = 0; i < 16; ++i) acc[i] += ks[i * 4 + ng][k] * wq;
  }
#pragma unroll
  for (int i = 0; i < 16; ++i)
    PK[((size_t)b * 64 + i * 4 + ng) * HH + h] = acc[i];
}

// ---------------- Wo fp32 -> bf16 ----------------
__global__ __launch_bounds__(256) void wo_bf16_kernel(const float* __restrict__ Wo,
                                                      unsigned short* __restrict__ WoB) {
  const int i = (blockIdx.x * 256 + threadIdx.x) * 4;
  const float4 v = *(const float4*)&Wo[i];
  WoB[i + 0] = f2bf(v.x);
  WoB[i + 1] = f2bf(v.y);
  WoB[i + 2] = f2bf(v.z);
  WoB[i + 3] = f2bf(v.w);
}

// -------- fused attn v2: split-bf16 MFMA scores -> softmax -> retrieve ------
// 64 tokens/block, 512 threads (8 waves), grid 256
__global__ __launch_bounds__(512) void attn_fused_kernel(
    const float* __restrict__ hs,      // [BT,2048]
    const float* __restrict__ PK,      // [B,64,2048]
    const float* __restrict__ vals,    // [B,64,256]
    const int* __restrict__ valid,     // [B,64]
    const int* __restrict__ hist,      // [BT]
    __hip_bfloat16* __restrict__ retrB) { // [BT,256]
  const int t0 = blockIdx.x * 64;
  const int b = t0 >> 12;
  const int tid = threadIdx.x;
  const int wid = tid >> 6, lane = tid & 63;
  const int fr = lane & 15, hi4 = lane >> 4;
  const int wr = wid & 1, wc = wid >> 1;   // wave tile: rows wr*32+32, cols wc*16

  __shared__ __align__(16) unsigned short Ah[2][64][64], Al[2][64][64];
  __shared__ __align__(16) unsigned short Bh[2][64][64], Bl[2][64][64];
  __shared__ float sc[64][72];

  const float* pkb = PK + (size_t)b * 64 * HH;
  const int sr = tid >> 3;            // staging row 0..63
  const int sc8 = tid & 7;            // staging 8-col group
  const int scs = (sc8 ^ (sr & 7)) * 8;  // swizzled col

  float4 va0, va1, vb0, vb1;
  floatx4 acc[2];
  acc[0] = (floatx4){0.f, 0.f, 0.f, 0.f};
  acc[1] = (floatx4){0.f, 0.f, 0.f, 0.f};

#define LOADREGS(ks) do { \
    const int k0 = (ks) * 64; \
    const float* pa = &hs[(size_t)(t0 + sr) * HH + k0 + sc8 * 8]; \
    va0 = *(const float4*)pa; va1 = *(const float4*)(pa + 4); \
    const float* pb = &pkb[(size_t)sr * HH + k0 + sc8 * 8]; \
    vb0 = *(const float4*)pb; vb1 = *(const float4*)(pb + 4); \
  } while (0)

#define WRITELDS(bf) do { \
    B8 h_, l_; \
    cvt8(va0, va1, h_, l_); \
    *(short8*)&Ah[bf][sr][scs] = h_.v; *(short8*)&Al[bf][sr][scs] = l_.v; \
    cvt8(vb0, vb1, h_, l_); \
    *(short8*)&Bh[bf][sr][scs] = h_.v; *(short8*)&Bl[bf][sr][scs] = l_.v; \
  } while (0)

  LOADREGS(0);
  WRITELDS(0);
  __syncthreads();

  for (int ks = 0; ks < 32; ++ks) {
    const int buf = ks & 1;
    if (ks < 31) LOADREGS(ks + 1);
    // frags
    short8 ahf[2][2], alf[2][2], bhf[2], blf[2];
#pragma unroll
    for (int kh = 0; kh < 2; ++kh) {
      const int c8 = kh * 4 + hi4;
      const int rb = wc * 16 + fr;
      const int cb = (c8 ^ (rb & 7)) * 8;
      bhf[kh] = *(const short8*)&Bh[buf][rb][cb];
      blf[kh] = *(const short8*)&Bl[buf][rb][cb];
#pragma unroll
      for (int mi = 0; mi < 2; ++mi) {
        const int ra = wr * 32 + mi * 16 + fr;
        const int ca = (c8 ^ (ra & 7)) * 8;
        ahf[mi][kh] = *(const short8*)&Ah[buf][ra][ca];
        alf[mi][kh] = *(const short8*)&Al[buf][ra][ca];
      }
    }
#pragma unroll
    for (int kh = 0; kh < 2; ++kh)
#pragma unroll
      for (int mi = 0; mi < 2; ++mi) {
        acc[mi] = __builtin_amdgcn_mfma_f32_16x16x32_bf16(ahf[mi][kh], bhf[kh], acc[mi], 0, 0, 0);
        acc[mi] = __builtin_amdgcn_mfma_f32_16x16x32_bf16(ahf[mi][kh], blf[kh], acc[mi], 0, 0, 0);
        acc[mi] = __builtin_amdgcn_mfma_f32_16x16x32_bf16(alf[mi][kh], bhf[kh], acc[mi], 0, 0, 0);
      }
    if (ks < 31) {
      __syncthreads();
      WRITELDS(buf ^ 1);
      __syncthreads();
    }
  }

  // write scores: C layout col=lane&15, row=(lane>>4)*4+reg
#pragma unroll
  for (int mi = 0; mi < 2; ++mi)
#pragma unroll
    for (int rr = 0; rr < 4; ++rr)
      sc[wr * 32 + mi * 16 + hi4 * 4 + rr][wc * 16 + fr] = acc[mi][rr];
  __syncthreads();

  // softmax: 8 waves x 8 tokens
  const int vmy = valid[b * 64 + lane];
  const unsigned long long bal = __ballot(vmy != 0);
  const float any = (bal != 0ull) ? 1.0f : 0.0f;
#pragma unroll
  for (int i = 0; i < 8; ++i) {
    const int tt = wid * 8 + i;
    float s = vmy ? sc[tt][lane] : NEGV;
    float m = s;
#pragma unroll
    for (int o = 32; o; o >>= 1) m = fmaxf(m, __shfl_xor(m, o));
    const float e = __expf(s - m);
    float sum = e;
#pragma unroll
    for (int o = 32; o; o >>= 1) sum += __shfl_xor(sum, o);
    sc[tt][lane] = e / sum * any;
  }
  __syncthreads();

  // retrieve: per wave, its 8 tokens in 2 chunks of 4
  const float* vb = vals + (size_t)b * 64 * 256;
#pragma unroll
  for (int c = 0; c < 2; ++c) {
    const int tb = wid * 8 + c * 4;
    float a4[4][4] = {};
    for (int n = 0; n < 64; ++n) {
      const float v0 = vb[n * 256 + lane];
      const float v1 = vb[n * 256 + 64 + lane];
      const float v2 = vb[n * 256 + 128 + lane];
      const float v3 = vb[n * 256 + 192 + lane];
#pragma unroll
      for (int i = 0; i < 4; ++i) {
        const float w = sc[tb + i][n];
        a4[i][0] += w * v0; a4[i][1] += w * v1;
        a4[i][2] += w * v2; a4[i][3] += w * v3;
      }
    }
#pragma unroll
    for (int i = 0; i < 4; ++i) {
      const int tok = t0 + tb + i;
      const float allowed = hist[tok] ? 0.0f : 1.0f;
#pragma unroll
      for (int j = 0; j < 4; ++j)
        retrB[(size_t)tok * 256 + j * 64 + lane] =
            __float2bfloat16(a4[i][j] * allowed);
    }
  }
#undef LOADREGS
#undef WRITELDS
}

// -------- GEMM2 + residual + LayerNorm fused -------------------------------
// block: 32 tokens x full 2048 cols, K=256. 512 threads (8 waves), grid 512.
__global__ __launch_bounds__(512) void gemm2_ln_kernel(
    const __hip_bfloat16* __restrict__ A,   // retrB [BT,256]
    const unsigned short* __restrict__ Bw,  // WoB [2048,256]
    const float* __restrict__ RES,          // hs
    const float* __restrict__ gamma,
    const float* __restrict__ beta,
    float* __restrict__ out) {
  const int m0 = blockIdx.x * 32;
  const int tid = threadIdx.x;
  const int wid = tid >> 6, lane = tid & 63;
  const int fr = lane & 15, hi4 = lane >> 4;

  __shared__ __align__(16) unsigned short As[32][264];
  __shared__ float gl[2048], bl[2048];
  __shared__ float part[32][8][2];
  __shared__ float stats[32][2];

  // stage A (32x256 bf16) + gamma/beta
#pragma unroll
  for (int it = 0; it < 2; ++it) {
    const int idx = tid + it * 512;
    const int r = idx >> 5, c8 = idx & 31;
    *(short8*)&As[r][c8 * 8] =
        *(const short8*)&A[(size_t)(m0 + r) * 256 + c8 * 8];
  }
#pragma unroll
  for (int it = 0; it < 4; ++it) {
    const int i = tid + it * 512;
    gl[i] = gamma[i];
    bl[i] = beta[i];
  }
  __syncthreads();

  floatx4 acc[2][16];
#pragma unroll
  for (int mi = 0; mi < 2; ++mi)
#pragma unroll
    for (int ni = 0; ni < 16; ++ni) acc[mi][ni] = (floatx4){0.f, 0.f, 0.f, 0.f};

  for (int kk = 0; kk < 8; ++kk) {
    short8 af[2];
    af[0] = *(const short8*)&As[fr][kk * 32 + hi4 * 8];
    af[1] = *(const short8*)&As[16 + fr][kk * 32 + hi4 * 8];
#pragma unroll
    for (int half = 0; half < 2; ++half) {
      short8 bfr[8];
#pragma unroll
      for (int j = 0; j < 8; ++j) {
        const int n = wid * 256 + (half * 8 + j) * 16 + fr;
        bfr[j] = *(const short8*)&Bw[(size_t)n * 256 + kk * 32 + hi4 * 8];
      }
#pragma unroll
      for (int j = 0; j < 8; ++j) {
        const int ni = half * 8 + j;
        acc[0][ni] = __builtin_amdgcn_mfma_f32_16x16x32_bf16(af[0], bfr[j], acc[0][ni], 0, 0, 0);
        acc[1][ni] = __builtin_amdgcn_mfma_f32_16x16x32_bf16(af[1], bfr[j], acc[1][ni], 0, 0, 0);
      }
    }
  }

  // residual add + per-row partial stats (each thread: 2mi x 4rr rows, 16 ni cols)
  float mysum[2][4] = {}, mysq[2][4] = {};
#pragma unroll
  for (int mi = 0; mi < 2; ++mi)
#pragma unroll
    for (int ni = 0; ni < 16; ++ni)
#pragma unroll
      for (int rr = 0; rr < 4; ++rr) {
        const int row = mi * 16 + hi4 * 4 + rr;
        const int col = wid * 256 + ni * 16 + fr;
        const float x = acc[mi][ni][rr] + RES[(size_t)(m0 + row) * HH + col];
        acc[mi][ni][rr] = x;
        mysum[mi][rr] += x;
        mysq[mi][rr] += x * x;
      }
#pragma unroll
  for (int mi = 0; mi < 2; ++mi)
#pragma unroll
    for (int rr = 0; rr < 4; ++rr) {
      float s = mysum[mi][rr], q = mysq[mi][rr];
#pragma unroll
      for (int o = 8; o; o >>= 1) {
        s += __shfl_xor(s, o);
        q += __shfl_xor(q, o);
      }
      if (fr == 0) {
        const int row = mi * 16 + hi4 * 4 + rr;
        part[row][wid][0] = s;
        part[row][wid][1] = q;
      }
    }
  __syncthreads();
  if (tid < 32) {
    float S = 0.f, Q = 0.f;
#pragma unroll
    for (int w = 0; w < 8; ++w) {
      S += part[tid][w][0];
      Q += part[tid][w][1];
    }
    const float mu = S * (1.0f / HH);
    const float var = Q * (1.0f / HH) - mu * mu;
    stats[tid][0] = mu;
    stats[tid][1] = rsqrtf(var + EPSV);
  }
  __syncthreads();

#pragma unroll
  for (int mi = 0; mi < 2; ++mi)
#pragma unroll
    for (int rr = 0; rr < 4; ++rr) {
      const int row = mi * 16 + hi4 * 4 + rr;
      const float mu = stats[row][0], inv = stats[row][1];
#pragma unroll
      for (int ni = 0; ni < 16; ++ni) {
        const int col = wid * 256 + ni * 16 + fr;
        out[(size_t)(m0 + row) * HH + col] =
            (acc[mi][ni][rr] - mu) * inv * gl[col] + bl[col];
      }
    }
}

extern "C" void kernel_launch(void* const* d_in, const int* in_sizes, int n_in,
                              void* d_out, int out_size, void* d_ws, size_t ws_size,
                              hipStream_t stream) {
  const float* hs    = (const float*)d_in[0];
  const float* keys  = (const float*)d_in[1];
  const float* vals  = (const float*)d_in[2];
  const float* Wq    = (const float*)d_in[3];
  const float* Wo    = (const float*)d_in[4];
  const float* gamma = (const float*)d_in[5];
  const float* beta  = (const float*)d_in[6];
  const void* valid_raw = d_in[7];
  const void* hist_raw  = d_in[8];
  float* out = (float*)d_out;

  char* w = (char*)d_ws;
  float* PK = (float*)w;                                        // 2 MB
  unsigned short* WoB = (unsigned short*)(w + (2u << 20));      // 1 MB
  __hip_bfloat16* retrB = (__hip_bfloat16*)(w + (3u << 20));    // 8 MB
  int* valid_int = (int*)(w + (11u << 20));
  int* hist_int = valid_int + BB * NSLOT;

  mask_convert_kernel<<<dim3(1), dim3(256), 0, stream>>>(valid_raw, hist_raw,
                                                         valid_int, hist_int);
  pk_kernel<<<dim3(128), dim3(256), 0, stream>>>(keys, Wq, PK);
  wo_bf16_kernel<<<dim3(512), dim3(256), 0, stream>>>(Wo, WoB);
  attn_fused_kernel<<<dim3(BT / 64), dim3(512), 0, stream>>>(
      hs, PK, vals, valid_int, hist_int, retrB);
  gemm2_ln_kernel<<<dim3(BT / 32), dim3(512), 0, stream>>>(
      retrB, WoB, hs, gamma, beta, out);
}

// Round 4
// 227.998 us; speedup vs baseline: 3.1044x; 1.2055x over previous
//
#include <hip/hip_runtime.h>
#include <hip/hip_bf16.h>

#define BB 4
#define TT 4096
#define HH 2048
#define NSLOT 64
#define KD 256
#define VD 256
#define BT (BB*TT)
#define NEGV (-1e9f)
#define EPSV 1e-5f

typedef __attribute__((ext_vector_type(8))) short short8;
typedef __attribute__((ext_vector_type(4))) float floatx4;

union B8 { short8 v; unsigned short u[8]; };

__device__ inline unsigned short f2bf(float x) {
  unsigned u = __float_as_uint(x);
  return (unsigned short)((u + 0x7FFFu + ((u >> 16) & 1u)) >> 16);
}
__device__ inline float bf2f(unsigned short h) {
  return __uint_as_float(((unsigned)h) << 16);
}
// 8 fp32 -> hi/lo bf16 (hi = RNE(x), lo = RNE(x - hi))
__device__ inline void cvt8(const float4 a, const float4 b, B8& h, B8& l) {
  const float f[8] = {a.x, a.y, a.z, a.w, b.x, b.y, b.z, b.w};
#pragma unroll
  for (int j = 0; j < 8; ++j) {
    unsigned short hh = f2bf(f[j]);
    h.u[j] = hh;
    l.u[j] = f2bf(f[j] - bf2f(hh));
  }
}

// ---------------- mask dtype detection + conversion (16 blocks) -------------
__global__ void mask_convert_kernel(const void* valid_raw, const void* hist_raw,
                                    int* valid_int, int* hist_int) {
  __shared__ int mode_s;
  const int tid = threadIdx.x;
  if (tid == 0) {
    const unsigned int* w = (const unsigned int*)valid_raw;
    int all01 = 1, anyfloat = 0;
    for (int i = 0; i < 64; ++i) {
      unsigned int x = w[i];
      if (x != 0u && x != 1u) all01 = 0;
      if (x == 0x3F800000u) anyfloat = 1;
    }
    mode_s = all01 ? 0 : (anyfloat ? 1 : 2);
  }
  __syncthreads();
  const int mode = mode_s;
  if (blockIdx.x == 0) {
    const int* vi = (const int*)valid_raw;
    const float* vf = (const float*)valid_raw;
    const unsigned char* vb = (const unsigned char*)valid_raw;
    for (int i = tid; i < BB * NSLOT; i += blockDim.x)
      valid_int[i] = (mode == 0) ? (vi[i] != 0)
                   : (mode == 1) ? (vf[i] != 0.0f)
                                 : (vb[i] != 0);
  }
  {
    const int* vi = (const int*)hist_raw;
    const float* vf = (const float*)hist_raw;
    const unsigned char* vb = (const unsigned char*)hist_raw;
    const int base = blockIdx.x * 1024;
    for (int i = tid; i < 1024; i += blockDim.x) {
      const int g = base + i;
      hist_int[g] = (mode == 0) ? (vi[g] != 0)
                  : (mode == 1) ? (vf[g] != 0.0f)
                                : (vb[g] != 0);
    }
  }
}

// ---------------- PK[b,n,h] = sum_k keys[b,n,k] * Wq[k,h]  (fp32) -----------
__global__ __launch_bounds__(256) void pk_kernel(const float* __restrict__ keys,
                                                 const float* __restrict__ Wq,
                                                 float* __restrict__ PK) {
  const int b = blockIdx.x >> 5;
  const int h0 = (blockIdx.x & 31) * 64;
  __shared__ float ks[64][260];   // pad: kills 16-way bank conflict
  const int tid = threadIdx.x;
  const float* kb = keys + (size_t)b * 64 * 256;
  for (int i = tid; i < 64 * 64; i += 256) {
    const int n = i >> 6, k4 = (i & 63) * 4;
    *(float4*)&ks[n][k4] = *(const float4*)&kb[n * 256 + k4];
  }
  __syncthreads();
  const int h = h0 + (tid & 63);
  const int ng = tid >> 6;
  float acc[16] = {};
  for (int k = 0; k < 256; ++k) {
    const float wq = Wq[(size_t)k * HH + h];
#pragma unroll
    for (int i = 0; i < 16; ++i) acc[i] += ks[i * 4 + ng][k] * wq;
  }
#pragma unroll
  for (int i = 0; i < 16; ++i)
    PK[((size_t)b * 64 + i * 4 + ng) * HH + h] = acc[i];
}

// -------- PK -> hi/lo bf16 MFMA-fragment layout -----------------------------
// PKh/PKl[((b*64+kc)*4+nt)*512 + lane*8] = PK[b][nt*16+fr][kc*32+hi4*8+j]
__global__ __launch_bounds__(64) void pkfrag_kernel(const float* __restrict__ PK,
                                                    unsigned short* __restrict__ PKh,
                                                    unsigned short* __restrict__ PKl) {
  const int b = blockIdx.x >> 6, kc = blockIdx.x & 63;
  const int lane = threadIdx.x, fr = lane & 15, hi4 = lane >> 4;
#pragma unroll
  for (int nt = 0; nt < 4; ++nt) {
    const float* src = &PK[((size_t)b * 64 + nt * 16 + fr) * HH + kc * 32 + hi4 * 8];
    const float4 a = *(const float4*)src;
    const float4 c = *(const float4*)(src + 4);
    B8 h, l;
    cvt8(a, c, h, l);
    const size_t off = (((size_t)(b * 64 + kc) * 4 + nt) * 64 + lane) * 8;
    *(short8*)&PKh[off] = h.v;
    *(short8*)&PKl[off] = l.v;
  }
}

// -------- V^T bf16 fragment layout ------------------------------------------
// VtF[((b*16+vt)*2+kc)*512 + lane*8] = vals[b][kc*32+hi4*8+j][vt*16+fr]
__global__ __launch_bounds__(64) void vtfrag_kernel(const float* __restrict__ vals,
                                                    unsigned short* __restrict__ VtF) {
  const int b = blockIdx.x >> 5, vt = (blockIdx.x >> 1) & 15, kc = blockIdx.x & 1;
  const int lane = threadIdx.x, fr = lane & 15, hi4 = lane >> 4;
  B8 t;
#pragma unroll
  for (int j = 0; j < 8; ++j) {
    const int n = kc * 32 + hi4 * 8 + j;
    t.u[j] = f2bf(vals[((size_t)b * 64 + n) * 256 + vt * 16 + fr]);
  }
  *(short8*)&VtF[(((size_t)b * 16 + vt) * 2 + kc) * 512 + lane * 8] = t.v;
}

// -------- Wo bf16 fragment layout -------------------------------------------
// WoF[(nt*8+kk)*512 + lane*8] = Wo[nt*16+fr][kk*32+hi4*8+j]
__global__ __launch_bounds__(64) void wofrag_kernel(const float* __restrict__ Wo,
                                                    unsigned short* __restrict__ WoF) {
  const int lane = threadIdx.x, fr = lane & 15, hi4 = lane >> 4;
  const int nt = blockIdx.x >> 3, kk = blockIdx.x & 7;
  const float* src = &Wo[(size_t)(nt * 16 + fr) * 256 + kk * 32 + hi4 * 8];
  const float4 a = *(const float4*)src;
  const float4 b2 = *(const float4*)(src + 4);
  B8 t;
  t.u[0] = f2bf(a.x); t.u[1] = f2bf(a.y); t.u[2] = f2bf(a.z); t.u[3] = f2bf(a.w);
  t.u[4] = f2bf(b2.x); t.u[5] = f2bf(b2.y); t.u[6] = f2bf(b2.z); t.u[7] = f2bf(b2.w);
  *(short8*)&WoF[(size_t)blockIdx.x * 512 + lane * 8] = t.v;
}

// -------- attn v3: per-wave MFMA scores (split-bf16) + softmax + MFMA PV ----
// block = 128 thr (2 waves), 16 tokens; waves split K; grid 1024
__global__ __launch_bounds__(128) void attn_kernel(
    const float* __restrict__ hs,          // [BT,2048]
    const unsigned short* __restrict__ PKh,
    const unsigned short* __restrict__ PKl,
    const unsigned short* __restrict__ VtF,
    const int* __restrict__ valid,
    const int* __restrict__ hist,
    __hip_bfloat16* __restrict__ retrB) {  // [BT,256]
  const int t0 = blockIdx.x * 16;
  const int b = blockIdx.x >> 8;
  const int tid = threadIdx.x;
  const int w = tid >> 6, lane = tid & 63;
  const int fr = lane & 15, hi4 = lane >> 4;

  __shared__ float S[2][16][68];
  __shared__ __align__(16) unsigned short P[16][72];

  floatx4 acc[4];
#pragma unroll
  for (int nt = 0; nt < 4; ++nt) acc[nt] = (floatx4){0.f, 0.f, 0.f, 0.f};

  // A row pointer for this lane (token = t0+fr, k offset hi4*8)
  const float* arow = &hs[(size_t)(t0 + fr) * HH + hi4 * 8];
  const int kc0 = w * 32;

  float4 va0 = *(const float4*)(arow + kc0 * 32);
  float4 va1 = *(const float4*)(arow + kc0 * 32 + 4);

  for (int c = 0; c < 32; ++c) {
    const int kc = kc0 + c;
    float4 na0, na1;
    if (c < 31) {
      na0 = *(const float4*)(arow + (kc + 1) * 32);
      na1 = *(const float4*)(arow + (kc + 1) * 32 + 4);
    }
    B8 ah, al;
    cvt8(va0, va1, ah, al);
    const size_t bbase = ((size_t)(b * 64 + kc) * 4) * 512 + lane * 8;
#pragma unroll
    for (int nt = 0; nt < 4; ++nt) {
      const short8 bh = *(const short8*)&PKh[bbase + nt * 512];
      const short8 bl = *(const short8*)&PKl[bbase + nt * 512];
      acc[nt] = __builtin_amdgcn_mfma_f32_16x16x32_bf16(ah.v, bh, acc[nt], 0, 0, 0);
      acc[nt] = __builtin_amdgcn_mfma_f32_16x16x32_bf16(al.v, bh, acc[nt], 0, 0, 0);
      acc[nt] = __builtin_amdgcn_mfma_f32_16x16x32_bf16(ah.v, bl, acc[nt], 0, 0, 0);
    }
    va0 = na0; va1 = na1;
  }

  // scores to LDS: token = hi4*4+rr, slot = nt*16+fr
#pragma unroll
  for (int nt = 0; nt < 4; ++nt)
#pragma unroll
    for (int rr = 0; rr < 4; ++rr)
      S[w][hi4 * 4 + rr][nt * 16 + fr] = acc[nt][rr];
  __syncthreads();

  // softmax: wave w handles tokens w*8..w*8+7; lane = slot
  const int vmy = valid[b * 64 + lane];
  const unsigned long long bal = __ballot(vmy != 0);
  const float any = (bal != 0ull) ? 1.0f : 0.0f;
#pragma unroll
  for (int i = 0; i < 8; ++i) {
    const int tt = w * 8 + i;
    float s = S[0][tt][lane] + S[1][tt][lane];
    s = vmy ? s : NEGV;
    float m = s;
#pragma unroll
    for (int o = 32; o; o >>= 1) m = fmaxf(m, __shfl_xor(m, o));
    const float e = __expf(s - m);
    float sum = e;
#pragma unroll
    for (int o = 32; o; o >>= 1) sum += __shfl_xor(sum, o);
    P[tt][lane] = f2bf(e / sum * any);
  }
  __syncthreads();

  // PV: wave w covers v-tiles w*8..w*8+7 (cols w*128..w*128+127)
  short8 pa0 = *(const short8*)&P[fr][hi4 * 8];
  short8 pa1 = *(const short8*)&P[fr][32 + hi4 * 8];
  floatx4 acc2[8];
#pragma unroll
  for (int v = 0; v < 8; ++v) acc2[v] = (floatx4){0.f, 0.f, 0.f, 0.f};
  const size_t vbase = ((size_t)b * 16) * 2 * 512 + lane * 8;
#pragma unroll
  for (int vtl = 0; vtl < 8; ++vtl) {
    const int vt = w * 8 + vtl;
    const short8 v0 = *(const short8*)&VtF[vbase + (vt * 2 + 0) * 512];
    const short8 v1 = *(const short8*)&VtF[vbase + (vt * 2 + 1) * 512];
    acc2[vtl] = __builtin_amdgcn_mfma_f32_16x16x32_bf16(pa0, v0, acc2[vtl], 0, 0, 0);
    acc2[vtl] = __builtin_amdgcn_mfma_f32_16x16x32_bf16(pa1, v1, acc2[vtl], 0, 0, 0);
  }
  float al4[4];
#pragma unroll
  for (int rr = 0; rr < 4; ++rr)
    al4[rr] = hist[t0 + hi4 * 4 + rr] ? 0.0f : 1.0f;
#pragma unroll
  for (int vtl = 0; vtl < 8; ++vtl)
#pragma unroll
    for (int rr = 0; rr < 4; ++rr)
      retrB[(size_t)(t0 + hi4 * 4 + rr) * 256 + (w * 8 + vtl) * 16 + fr] =
          __float2bfloat16(acc2[vtl][rr] * al4[rr]);
}

// -------- GEMM2 + residual + LayerNorm fused --------------------------------
// block: 16 tokens x 2048 cols, 512 thr (8 waves, 256 cols each), grid 1024
__global__ __launch_bounds__(512) void gemm2_ln_kernel(
    const __hip_bfloat16* __restrict__ A,   // retrB [BT,256]
    const unsigned short* __restrict__ WoF, // frag layout
    const float* __restrict__ RES,          // hs
    const float* __restrict__ gamma,
    const float* __restrict__ beta,
    float* __restrict__ out) {
  const int m0 = blockIdx.x * 16;
  const int tid = threadIdx.x;
  const int wid = tid >> 6, lane = tid & 63;
  const int fr = lane & 15, hi4 = lane >> 4;

  __shared__ __align__(16) unsigned short As[16][264];
  __shared__ float part[16][8][2];
  __shared__ float stats[16][2];

  {
    const int r = tid >> 5, c8 = tid & 31;
    *(short8*)&As[r][c8 * 8] =
        *(const short8*)&A[(size_t)(m0 + r) * 256 + c8 * 8];
  }
  __syncthreads();

  floatx4 acc[16];
#pragma unroll
  for (int j = 0; j < 16; ++j) acc[j] = (floatx4){0.f, 0.f, 0.f, 0.f};

  for (int kk = 0; kk < 8; ++kk) {
    const short8 af = *(const short8*)&As[fr][kk * 32 + hi4 * 8];
#pragma unroll
    for (int j = 0; j < 16; ++j) {
      const int nt = wid * 16 + j;
      const short8 bf = *(const short8*)&WoF[((size_t)nt * 8 + kk) * 512 + lane * 8];
      acc[j] = __builtin_amdgcn_mfma_f32_16x16x32_bf16(af, bf, acc[j], 0, 0, 0);
    }
  }

  // residual + per-row partial stats (token = hi4*4+rr)
  float msum[4] = {}, msq[4] = {};
#pragma unroll
  for (int j = 0; j < 16; ++j) {
#pragma unroll
    for (int rr = 0; rr < 4; ++rr) {
      const int row = hi4 * 4 + rr;
      const int col = wid * 256 + j * 16 + fr;
      const float x = acc[j][rr] + RES[(size_t)(m0 + row) * HH + col];
      acc[j][rr] = x;
      msum[rr] += x;
      msq[rr] += x * x;
    }
  }
#pragma unroll
  for (int rr = 0; rr < 4; ++rr) {
    float s = msum[rr], q = msq[rr];
#pragma unroll
    for (int o = 8; o; o >>= 1) {
      s += __shfl_xor(s, o);
      q += __shfl_xor(q, o);
    }
    if (fr == 0) {
      part[hi4 * 4 + rr][wid][0] = s;
      part[hi4 * 4 + rr][wid][1] = q;
    }
  }
  __syncthreads();
  if (tid < 16) {
    float S = 0.f, Q = 0.f;
#pragma unroll
    for (int w = 0; w < 8; ++w) {
      S += part[tid][w][0];
      Q += part[tid][w][1];
    }
    const float mu = S * (1.0f / HH);
    const float var = Q * (1.0f / HH) - mu * mu;
    stats[tid][0] = mu;
    stats[tid][1] = rsqrtf(var + EPSV);
  }
  __syncthreads();

#pragma unroll
  for (int j = 0; j < 16; ++j) {
    const int col = wid * 256 + j * 16 + fr;
    const float g = gamma[col], bt = beta[col];
#pragma unroll
    for (int rr = 0; rr < 4; ++rr) {
      const int row = hi4 * 4 + rr;
      out[(size_t)(m0 + row) * HH + col] =
          (acc[j][rr] - stats[row][0]) * stats[row][1] * g + bt;
    }
  }
}

extern "C" void kernel_launch(void* const* d_in, const int* in_sizes, int n_in,
                              void* d_out, int out_size, void* d_ws, size_t ws_size,
                              hipStream_t stream) {
  const float* hs    = (const float*)d_in[0];
  const float* keys  = (const float*)d_in[1];
  const float* vals  = (const float*)d_in[2];
  const float* Wq    = (const float*)d_in[3];
  const float* Wo    = (const float*)d_in[4];
  const float* gamma = (const float*)d_in[5];
  const float* beta  = (const float*)d_in[6];
  const void* valid_raw = d_in[7];
  const void* hist_raw  = d_in[8];
  float* out = (float*)d_out;

  char* w = (char*)d_ws;
  float* PK            = (float*)w;                         // 2 MB
  unsigned short* PKh  = (unsigned short*)(w + (2u << 20)); // 1 MB
  unsigned short* PKl  = (unsigned short*)(w + (3u << 20)); // 1 MB
  unsigned short* VtF  = (unsigned short*)(w + (4u << 20)); // 256 KB
  unsigned short* WoF  = (unsigned short*)(w + (5u << 20)); // 1 MB
  __hip_bfloat16* retrB = (__hip_bfloat16*)(w + (6u << 20)); // 8 MB
  int* valid_int = (int*)(w + (15u << 20));
  int* hist_int  = valid_int + BB * NSLOT;

  mask_convert_kernel<<<dim3(16), dim3(256), 0, stream>>>(valid_raw, hist_raw,
                                                          valid_int, hist_int);
  pk_kernel<<<dim3(128), dim3(256), 0, stream>>>(keys, Wq, PK);
  pkfrag_kernel<<<dim3(256), dim3(64), 0, stream>>>(PK, PKh, PKl);
  vtfrag_kernel<<<dim3(128), dim3(64), 0, stream>>>(vals, VtF);
  wofrag_kernel<<<dim3(1024), dim3(64), 0, stream>>>(Wo, WoF);
  attn_kernel<<<dim3(BT / 16), dim3(128), 0, stream>>>(
      hs, PKh, PKl, VtF, valid_int, hist_int, retrB);
  gemm2_ln_kernel<<<dim3(BT / 16), dim3(512), 0, stream>>>(
      retrB, WoF, hs, gamma, beta, out);
}

// Round 5
// 205.124 us; speedup vs baseline: 3.4506x; 1.1115x over previous
//
#include <hip/hip_runtime.h>
#include <hip/hip_bf16.h>

#define BB 4
#define TT 4096
#define HH 2048
#define NSLOT 64
#define KD 256
#define VD 256
#define BT (BB*TT)
#define NEGV (-1e9f)
#define EPSV 1e-5f

typedef __attribute__((ext_vector_type(8))) short short8;
typedef __attribute__((ext_vector_type(4))) float floatx4;

union B8 { short8 v; unsigned short u[8]; };

__device__ inline unsigned short f2bf(float x) {
  unsigned u = __float_as_uint(x);
  return (unsigned short)((u + 0x7FFFu + ((u >> 16) & 1u)) >> 16);
}
__device__ inline float bf2f(unsigned short h) {
  return __uint_as_float(((unsigned)h) << 16);
}
// 8 fp32 -> hi/lo bf16 (hi = RNE(x), lo = RNE(x - hi))
__device__ inline void cvt8(const float4 a, const float4 b, B8& h, B8& l) {
  const float f[8] = {a.x, a.y, a.z, a.w, b.x, b.y, b.z, b.w};
#pragma unroll
  for (int j = 0; j < 8; ++j) {
    unsigned short hh = f2bf(f[j]);
    h.u[j] = hh;
    l.u[j] = f2bf(f[j] - bf2f(hh));
  }
}

// ---------------- mask dtype detection + conversion (16 blocks) -------------
__global__ void mask_convert_kernel(const void* valid_raw, const void* hist_raw,
                                    int* valid_int, int* hist_int) {
  __shared__ int mode_s;
  const int tid = threadIdx.x;
  if (tid == 0) {
    const unsigned int* w = (const unsigned int*)valid_raw;
    int all01 = 1, anyfloat = 0;
    for (int i = 0; i < 64; ++i) {
      unsigned int x = w[i];
      if (x != 0u && x != 1u) all01 = 0;
      if (x == 0x3F800000u) anyfloat = 1;
    }
    mode_s = all01 ? 0 : (anyfloat ? 1 : 2);
  }
  __syncthreads();
  const int mode = mode_s;
  if (blockIdx.x == 0) {
    const int* vi = (const int*)valid_raw;
    const float* vf = (const float*)valid_raw;
    const unsigned char* vb = (const unsigned char*)valid_raw;
    for (int i = tid; i < BB * NSLOT; i += blockDim.x)
      valid_int[i] = (mode == 0) ? (vi[i] != 0)
                   : (mode == 1) ? (vf[i] != 0.0f)
                                 : (vb[i] != 0);
  }
  {
    const int* vi = (const int*)hist_raw;
    const float* vf = (const float*)hist_raw;
    const unsigned char* vb = (const unsigned char*)hist_raw;
    const int base = blockIdx.x * 1024;
    for (int i = tid; i < 1024; i += blockDim.x) {
      const int g = base + i;
      hist_int[g] = (mode == 0) ? (vi[g] != 0)
                  : (mode == 1) ? (vf[g] != 0.0f)
                                : (vb[g] != 0);
    }
  }
}

// ---------------- PK[b,n,h] = sum_k keys[b,n,k] * Wq[k,h]  (fp32) -----------
__global__ __launch_bounds__(256) void pk_kernel(const float* __restrict__ keys,
                                                 const float* __restrict__ Wq,
                                                 float* __restrict__ PK) {
  const int b = blockIdx.x >> 5;
  const int h0 = (blockIdx.x & 31) * 64;
  __shared__ float ks[64][260];
  const int tid = threadIdx.x;
  const float* kb = keys + (size_t)b * 64 * 256;
  for (int i = tid; i < 64 * 64; i += 256) {
    const int n = i >> 6, k4 = (i & 63) * 4;
    *(float4*)&ks[n][k4] = *(const float4*)&kb[n * 256 + k4];
  }
  __syncthreads();
  const int h = h0 + (tid & 63);
  const int ng = tid >> 6;
  float acc[16] = {};
  for (int k = 0; k < 256; ++k) {
    const float wq = Wq[(size_t)k * HH + h];
#pragma unroll
    for (int i = 0; i < 16; ++i) acc[i] += ks[i * 4 + ng][k] * wq;
  }
#pragma unroll
  for (int i = 0; i < 16; ++i)
    PK[((size_t)b * 64 + i * 4 + ng) * HH + h] = acc[i];
}

// -------- PK -> hi/lo bf16 MFMA-fragment layout -----------------------------
__global__ __launch_bounds__(64) void pkfrag_kernel(const float* __restrict__ PK,
                                                    unsigned short* __restrict__ PKh,
                                                    unsigned short* __restrict__ PKl) {
  const int b = blockIdx.x >> 6, kc = blockIdx.x & 63;
  const int lane = threadIdx.x, fr = lane & 15, hi4 = lane >> 4;
#pragma unroll
  for (int nt = 0; nt < 4; ++nt) {
    const float* src = &PK[((size_t)b * 64 + nt * 16 + fr) * HH + kc * 32 + hi4 * 8];
    const float4 a = *(const float4*)src;
    const float4 c = *(const float4*)(src + 4);
    B8 h, l;
    cvt8(a, c, h, l);
    const size_t off = (((size_t)(b * 64 + kc) * 4 + nt) * 64 + lane) * 8;
    *(short8*)&PKh[off] = h.v;
    *(short8*)&PKl[off] = l.v;
  }
}

// -------- V^T bf16 fragment layout ------------------------------------------
__global__ __launch_bounds__(64) void vtfrag_kernel(const float* __restrict__ vals,
                                                    unsigned short* __restrict__ VtF) {
  const int b = blockIdx.x >> 5, vt = (blockIdx.x >> 1) & 15, kc = blockIdx.x & 1;
  const int lane = threadIdx.x, fr = lane & 15, hi4 = lane >> 4;
  B8 t;
#pragma unroll
  for (int j = 0; j < 8; ++j) {
    const int n = kc * 32 + hi4 * 8 + j;
    t.u[j] = f2bf(vals[((size_t)b * 64 + n) * 256 + vt * 16 + fr]);
  }
  *(short8*)&VtF[(((size_t)b * 16 + vt) * 2 + kc) * 512 + lane * 8] = t.v;
}

// -------- Wo bf16 fragment layout -------------------------------------------
__global__ __launch_bounds__(64) void wofrag_kernel(const float* __restrict__ Wo,
                                                    unsigned short* __restrict__ WoF) {
  const int lane = threadIdx.x, fr = lane & 15, hi4 = lane >> 4;
  const int nt = blockIdx.x >> 3, kk = blockIdx.x & 7;
  const float* src = &Wo[(size_t)(nt * 16 + fr) * 256 + kk * 32 + hi4 * 8];
  const float4 a = *(const float4*)src;
  const float4 b2 = *(const float4*)(src + 4);
  B8 t;
  t.u[0] = f2bf(a.x); t.u[1] = f2bf(a.y); t.u[2] = f2bf(a.z); t.u[3] = f2bf(a.w);
  t.u[4] = f2bf(b2.x); t.u[5] = f2bf(b2.y); t.u[6] = f2bf(b2.z); t.u[7] = f2bf(b2.w);
  *(short8*)&WoF[(size_t)blockIdx.x * 512 + lane * 8] = t.v;
}

// -------- attn v5: LDS-staged coalesced A (pre-converted hi/lo), N-split ----
// block = 256 thr (4 waves), 32 tokens; wave w owns slots w*16..+16, full K.
// grid 512
__global__ __launch_bounds__(256) void attn_kernel(
    const float* __restrict__ hs,          // [BT,2048]
    const unsigned short* __restrict__ PKh,
    const unsigned short* __restrict__ PKl,
    const unsigned short* __restrict__ VtF,
    const int* __restrict__ valid,
    const int* __restrict__ hist,
    __hip_bfloat16* __restrict__ retrB) {  // [BT,256]
  const int t0 = blockIdx.x * 32;
  const int b = blockIdx.x >> 7;           // 128 blocks per batch
  const int tid = threadIdx.x;
  const int w = tid >> 6, lane = tid & 63;
  const int fr = lane & 15, hi4 = lane >> 4;

  __shared__ __align__(16) unsigned short Ah_s[2][32][32], Al_s[2][32][32];
  __shared__ float S[32][68];
  __shared__ __align__(16) unsigned short P[32][80];

  // staging: threads 0..127, one 8-float group each
  const int sr = tid >> 2;        // token 0..31
  const int sg = tid & 3;         // col group (8 floats)
  const float* grow = &hs[(size_t)(t0 + sr) * HH + sg * 8];

  floatx4 acc[2];
  acc[0] = (floatx4){0.f, 0.f, 0.f, 0.f};
  acc[1] = (floatx4){0.f, 0.f, 0.f, 0.f};

  float4 va0, va1;
  if (tid < 128) {
    va0 = *(const float4*)grow;
    va1 = *(const float4*)(grow + 4);
  }

  const size_t pkstep = 4 * 512;
  size_t pkoff = ((size_t)(b * 64) * 4 + w) * 512 + lane * 8;
  short8 bh = *(const short8*)&PKh[pkoff];
  short8 bl = *(const short8*)&PKl[pkoff];

  for (int c = 0; c < 64; ++c) {
    const int buf = c & 1;
    if (tid < 128) {
      B8 h_, l_;
      cvt8(va0, va1, h_, l_);
      *(short8*)&Ah_s[buf][sr][sg * 8] = h_.v;
      *(short8*)&Al_s[buf][sr][sg * 8] = l_.v;
    }
    __syncthreads();
    if (tid < 128 && c < 63) {
      va0 = *(const float4*)(grow + (c + 1) * 32);
      va1 = *(const float4*)(grow + (c + 1) * 32 + 4);
    }
    short8 bh_n, bl_n;
    if (c < 63) {
      bh_n = *(const short8*)&PKh[pkoff + pkstep];
      bl_n = *(const short8*)&PKl[pkoff + pkstep];
    }
    pkoff += pkstep;
#pragma unroll
    for (int mf = 0; mf < 2; ++mf) {
      const short8 ah = *(const short8*)&Ah_s[buf][mf * 16 + fr][hi4 * 8];
      const short8 al = *(const short8*)&Al_s[buf][mf * 16 + fr][hi4 * 8];
      acc[mf] = __builtin_amdgcn_mfma_f32_16x16x32_bf16(ah, bh, acc[mf], 0, 0, 0);
      acc[mf] = __builtin_amdgcn_mfma_f32_16x16x32_bf16(al, bh, acc[mf], 0, 0, 0);
      acc[mf] = __builtin_amdgcn_mfma_f32_16x16x32_bf16(ah, bl, acc[mf], 0, 0, 0);
    }
    bh = bh_n;
    bl = bl_n;
  }

  // scores: token = mf*16+hi4*4+rr, slot = w*16+fr
#pragma unroll
  for (int mf = 0; mf < 2; ++mf)
#pragma unroll
    for (int rr = 0; rr < 4; ++rr)
      S[mf * 16 + hi4 * 4 + rr][w * 16 + fr] = acc[mf][rr];
  __syncthreads();

  // softmax: wave w -> tokens w*8..w*8+7; lane = slot
  const int vmy = valid[b * 64 + lane];
  const unsigned long long bal = __ballot(vmy != 0);
  const float any = (bal != 0ull) ? 1.0f : 0.0f;
#pragma unroll
  for (int i = 0; i < 8; ++i) {
    const int tt = w * 8 + i;
    float s = vmy ? S[tt][lane] : NEGV;
    float m = s;
#pragma unroll
    for (int o = 32; o; o >>= 1) m = fmaxf(m, __shfl_xor(m, o));
    const float e = __expf(s - m);
    float sum = e;
#pragma unroll
    for (int o = 32; o; o >>= 1) sum += __shfl_xor(sum, o);
    P[tt][lane] = f2bf(e / sum * any);
  }
  __syncthreads();

  // PV: wave w -> v-tiles w*4..w*4+3 (cols w*64..+64)
  short8 pa[2][2];
#pragma unroll
  for (int mf = 0; mf < 2; ++mf)
#pragma unroll
    for (int ks = 0; ks < 2; ++ks)
      pa[mf][ks] = *(const short8*)&P[mf * 16 + fr][ks * 32 + hi4 * 8];
  floatx4 acc2[2][4];
#pragma unroll
  for (int mf = 0; mf < 2; ++mf)
#pragma unroll
    for (int j = 0; j < 4; ++j) acc2[mf][j] = (floatx4){0.f, 0.f, 0.f, 0.f};
  const size_t vbase = (size_t)(b * 16) * 2 * 512 + lane * 8;
#pragma unroll
  for (int j = 0; j < 4; ++j) {
    const int vt = w * 4 + j;
    const short8 v0 = *(const short8*)&VtF[vbase + (size_t)(vt * 2 + 0) * 512];
    const short8 v1 = *(const short8*)&VtF[vbase + (size_t)(vt * 2 + 1) * 512];
#pragma unroll
    for (int mf = 0; mf < 2; ++mf) {
      acc2[mf][j] = __builtin_amdgcn_mfma_f32_16x16x32_bf16(pa[mf][0], v0, acc2[mf][j], 0, 0, 0);
      acc2[mf][j] = __builtin_amdgcn_mfma_f32_16x16x32_bf16(pa[mf][1], v1, acc2[mf][j], 0, 0, 0);
    }
  }
#pragma unroll
  for (int mf = 0; mf < 2; ++mf)
#pragma unroll
    for (int rr = 0; rr < 4; ++rr) {
      const int tok = t0 + mf * 16 + hi4 * 4 + rr;
      const float allowed = hist[tok] ? 0.0f : 1.0f;
#pragma unroll
      for (int j = 0; j < 4; ++j)
        retrB[(size_t)tok * 256 + (w * 4 + j) * 16 + fr] =
            __float2bfloat16(acc2[mf][j][rr] * allowed);
    }
}

// -------- GEMM2 + residual + LayerNorm fused, B-frag prefetch pipeline ------
// block: 16 tokens x 2048 cols, 512 thr (8 waves, 256 cols each), grid 1024
__global__ __launch_bounds__(512, 2) void gemm2_ln_kernel(
    const __hip_bfloat16* __restrict__ A,   // retrB [BT,256]
    const unsigned short* __restrict__ WoF, // frag layout
    const float* __restrict__ RES,          // hs
    const float* __restrict__ gamma,
    const float* __restrict__ beta,
    float* __restrict__ out) {
  const int m0 = blockIdx.x * 16;
  const int tid = threadIdx.x;
  const int wid = tid >> 6, lane = tid & 63;
  const int fr = lane & 15, hi4 = lane >> 4;

  __shared__ __align__(16) unsigned short As[16][264];
  __shared__ float part[16][8][2];
  __shared__ float stats[16][2];

  {
    const int r = tid >> 5, c8 = tid & 31;
    *(short8*)&As[r][c8 * 8] =
        *(const short8*)&A[(size_t)(m0 + r) * 256 + c8 * 8];
  }

  floatx4 acc[16];
#pragma unroll
  for (int j = 0; j < 16; ++j) acc[j] = (floatx4){0.f, 0.f, 0.f, 0.f};

  // preload kk=0 B frags
  const unsigned short* wbase = &WoF[(size_t)(wid * 16) * 8 * 512 + lane * 8];
  short8 bcur[16];
#pragma unroll
  for (int j = 0; j < 16; ++j)
    bcur[j] = *(const short8*)&wbase[(size_t)j * 8 * 512];
  __syncthreads();

#pragma unroll
  for (int kk = 0; kk < 8; ++kk) {
    short8 bnxt[16];
    if (kk < 7) {
#pragma unroll
      for (int j = 0; j < 16; ++j)
        bnxt[j] = *(const short8*)&wbase[(size_t)j * 8 * 512 + (kk + 1) * 512];
    }
    const short8 af = *(const short8*)&As[fr][kk * 32 + hi4 * 8];
#pragma unroll
    for (int j = 0; j < 16; ++j)
      acc[j] = __builtin_amdgcn_mfma_f32_16x16x32_bf16(af, bcur[j], acc[j], 0, 0, 0);
    if (kk < 7) {
#pragma unroll
      for (int j = 0; j < 16; ++j) bcur[j] = bnxt[j];
    }
  }

  // residual + per-row partial stats (token = hi4*4+rr)
  float msum[4] = {}, msq[4] = {};
#pragma unroll
  for (int j = 0; j < 16; ++j) {
#pragma unroll
    for (int rr = 0; rr < 4; ++rr) {
      const int row = hi4 * 4 + rr;
      const int col = wid * 256 + j * 16 + fr;
      const float x = acc[j][rr] + RES[(size_t)(m0 + row) * HH + col];
      acc[j][rr] = x;
      msum[rr] += x;
      msq[rr] += x * x;
    }
  }
#pragma unroll
  for (int rr = 0; rr < 4; ++rr) {
    float s = msum[rr], q = msq[rr];
#pragma unroll
    for (int o = 8; o; o >>= 1) {
      s += __shfl_xor(s, o);
      q += __shfl_xor(q, o);
    }
    if (fr == 0) {
      part[hi4 * 4 + rr][wid][0] = s;
      part[hi4 * 4 + rr][wid][1] = q;
    }
  }
  __syncthreads();
  if (tid < 16) {
    float S = 0.f, Q = 0.f;
#pragma unroll
    for (int w = 0; w < 8; ++w) {
      S += part[tid][w][0];
      Q += part[tid][w][1];
    }
    const float mu = S * (1.0f / HH);
    const float var = Q * (1.0f / HH) - mu * mu;
    stats[tid][0] = mu;
    stats[tid][1] = rsqrtf(var + EPSV);
  }
  __syncthreads();

#pragma unroll
  for (int j = 0; j < 16; ++j) {
    const int col = wid * 256 + j * 16 + fr;
    const float g = gamma[col], bt = beta[col];
#pragma unroll
    for (int rr = 0; rr < 4; ++rr) {
      const int row = hi4 * 4 + rr;
      out[(size_t)(m0 + row) * HH + col] =
          (acc[j][rr] - stats[row][0]) * stats[row][1] * g + bt;
    }
  }
}

extern "C" void kernel_launch(void* const* d_in, const int* in_sizes, int n_in,
                              void* d_out, int out_size, void* d_ws, size_t ws_size,
                              hipStream_t stream) {
  const float* hs    = (const float*)d_in[0];
  const float* keys  = (const float*)d_in[1];
  const float* vals  = (const float*)d_in[2];
  const float* Wq    = (const float*)d_in[3];
  const float* Wo    = (const float*)d_in[4];
  const float* gamma = (const float*)d_in[5];
  const float* beta  = (const float*)d_in[6];
  const void* valid_raw = d_in[7];
  const void* hist_raw  = d_in[8];
  float* out = (float*)d_out;

  char* w = (char*)d_ws;
  float* PK            = (float*)w;                         // 2 MB
  unsigned short* PKh  = (unsigned short*)(w + (2u << 20)); // 1 MB
  unsigned short* PKl  = (unsigned short*)(w + (3u << 20)); // 1 MB
  unsigned short* VtF  = (unsigned short*)(w + (4u << 20)); // 256 KB
  unsigned short* WoF  = (unsigned short*)(w + (5u << 20)); // 1 MB
  __hip_bfloat16* retrB = (__hip_bfloat16*)(w + (6u << 20)); // 8 MB
  int* valid_int = (int*)(w + (15u << 20));
  int* hist_int  = valid_int + BB * NSLOT;

  mask_convert_kernel<<<dim3(16), dim3(256), 0, stream>>>(valid_raw, hist_raw,
                                                          valid_int, hist_int);
  pk_kernel<<<dim3(128), dim3(256), 0, stream>>>(keys, Wq, PK);
  pkfrag_kernel<<<dim3(256), dim3(64), 0, stream>>>(PK, PKh, PKl);
  vtfrag_kernel<<<dim3(128), dim3(64), 0, stream>>>(vals, VtF);
  wofrag_kernel<<<dim3(1024), dim3(64), 0, stream>>>(Wo, WoF);
  attn_kernel<<<dim3(BT / 32), dim3(256), 0, stream>>>(
      hs, PKh, PKl, VtF, valid_int, hist_int, retrB);
  gemm2_ln_kernel<<<dim3(BT / 16), dim3(512), 0, stream>>>(
      retrB, WoF, hs, gamma, beta, out);
}